// Round 1
// baseline (1073.051 us; speedup 1.0000x reference)
//
#include <hip/hip_runtime.h>
#include <hip/hip_bf16.h>

#define N_USERS   50000
#define N_ITEMS   50000
#define N_ENT     100000
#define N_RELV    32
#define NE        2000000
#define NNI       1000000
#define DD        64

// ---------------------------------------------------------------------------
// Stage 2: entity-graph scatter-mean accumulate.
// One 64-lane wave per edge; lane = feature dim.
// ---------------------------------------------------------------------------
__global__ void edge_agg_kernel(const float* __restrict__ ent,
                                const int* __restrict__ head,
                                const int* __restrict__ tail,
                                const int* __restrict__ etype,
                                const float* __restrict__ wgt,
                                float* __restrict__ acc,
                                float* __restrict__ cnt) {
    const int lane = threadIdx.x & 63;
    const int wpb  = blockDim.x >> 6;
    int wave       = blockIdx.x * wpb + (threadIdx.x >> 6);
    const int nw   = gridDim.x * wpb;
    for (int e = wave; e < NE; e += nw) {
        const int h = head[e];
        const int t = tail[e];
        const int r = etype[e];
        const float v = ent[(size_t)t * DD + lane] * wgt[r * DD + lane];
        unsafeAtomicAdd(&acc[(size_t)h * DD + lane], v);
        if (lane == 0) unsafeAtomicAdd(&cnt[h], 1.0f);
    }
}

// ---------------------------------------------------------------------------
// Stage 3: user->item scatter-mean accumulate (weight row 0).
// ---------------------------------------------------------------------------
__global__ void user_item_kernel(const float* __restrict__ uemb,
                                 const int* __restrict__ mrow,
                                 const int* __restrict__ mcol,
                                 const float* __restrict__ wgt,
                                 float* __restrict__ acc,
                                 float* __restrict__ cnt) {
    const int lane = threadIdx.x & 63;
    const int wpb  = blockDim.x >> 6;
    int wave       = blockIdx.x * wpb + (threadIdx.x >> 6);
    const int nw   = gridDim.x * wpb;
    const float w0 = wgt[lane];   // weight[0][lane]
    for (int i = wave; i < NNI; i += nw) {
        const int r = mrow[i];
        const int c = mcol[i];
        const float v = uemb[(size_t)r * DD + lane] * w0;
        unsafeAtomicAdd(&acc[(size_t)c * DD + lane], v);
        if (lane == 0) unsafeAtomicAdd(&cnt[c], 1.0f);
    }
}

// ---------------------------------------------------------------------------
// Stage 4a: finalize entity scatter-mean.
// rows < N_ITEMS  -> write back into acc (item_kg_agg, consumed by gate)
// rows >= N_ITEMS -> write att_kg_agg directly into d_out (same row offset)
// ---------------------------------------------------------------------------
__global__ void finalize_entity_kernel(float* __restrict__ acc,
                                       const float* __restrict__ cnt,
                                       float* __restrict__ out) {
    const size_t idx = (size_t)blockIdx.x * blockDim.x + threadIdx.x;
    if (idx >= (size_t)N_ENT * DD) return;
    const int row = (int)(idx >> 6);
    const float inv = 1.0f / fmaxf(cnt[row], 1.0f);
    const float v = acc[idx] * inv;
    if (row < N_ITEMS) acc[idx] = v;
    else               out[idx] = v;
}

// Stage 4b: finalize i_u_agg in place.
__global__ void finalize_iu_kernel(float* __restrict__ acc,
                                   const float* __restrict__ cnt) {
    const size_t idx = (size_t)blockIdx.x * blockDim.x + threadIdx.x;
    if (idx >= (size_t)N_ITEMS * DD) return;
    const int row = (int)(idx >> 6);
    acc[idx] *= 1.0f / fmaxf(cnt[row], 1.0f);
}

// ---------------------------------------------------------------------------
// Stage 5: gate + fusion. 4 items per 256-thread block; lane j owns output
// dim j. Gate matrices staged in LDS with pitch 65 (bank = (j+k)%32, 2-way
// aliasing = free on CDNA4).
// ---------------------------------------------------------------------------
__global__ void gate_fusion_kernel(const float* __restrict__ kg,
                                   const float* __restrict__ iu,
                                   const float* __restrict__ g1,
                                   const float* __restrict__ g2,
                                   float* __restrict__ out) {
    __shared__ float G1[64 * 65];
    __shared__ float G2[64 * 65];
    __shared__ float xs1[4][64];
    __shared__ float xs2[4][64];

    const int tid = threadIdx.x;
    for (int i = tid; i < 64 * 64; i += 256) {
        const int r = i >> 6, c = i & 63;
        G1[r * 65 + c] = g1[i];
        G2[r * 65 + c] = g2[i];
    }

    const int il   = tid >> 6;        // item within block (0..3)
    const int j    = tid & 63;        // output dim
    const int item = blockIdx.x * 4 + il;

    const float x1 = kg[(size_t)item * DD + j];
    const float x2 = iu[(size_t)item * DD + j];
    xs1[il][j] = x1;
    xs2[il][j] = x2;
    __syncthreads();

    float s = 0.0f;
    #pragma unroll
    for (int k = 0; k < 64; ++k) {
        s += xs1[il][k] * G1[j * 65 + k];
        s += xs2[il][k] * G2[j * 65 + k];
    }
    const float gi = 1.0f / (1.0f + __expf(-s));
    out[(size_t)item * DD + j] = gi * x1 + (1.0f - gi) * x2;
}

// ---------------------------------------------------------------------------
// Stage 6: user_agg = segment_sum(fusion[mat_col], mat_row).
// fusion is read back from d_out[0 : N_ITEMS*64).
// ---------------------------------------------------------------------------
__global__ void user_scatter_kernel(const float* __restrict__ fus,
                                    const int* __restrict__ mrow,
                                    const int* __restrict__ mcol,
                                    float* __restrict__ uacc) {
    const int lane = threadIdx.x & 63;
    const int wpb  = blockDim.x >> 6;
    int wave       = blockIdx.x * wpb + (threadIdx.x >> 6);
    const int nw   = gridDim.x * wpb;
    for (int i = wave; i < NNI; i += nw) {
        const int r = mrow[i];
        const int c = mcol[i];
        unsafeAtomicAdd(&uacc[(size_t)r * DD + lane], fus[(size_t)c * DD + lane]);
    }
}

extern "C" void kernel_launch(void* const* d_in, const int* in_sizes, int n_in,
                              void* d_out, int out_size, void* d_ws, size_t ws_size,
                              hipStream_t stream) {
    const float* entity_emb = (const float*)d_in[0];   // (100000, 64)
    const float* user_emb   = (const float*)d_in[1];   // (50000, 64)
    const int*   edge_index = (const int*)d_in[2];     // (2, E)
    const int*   edge_type  = (const int*)d_in[3];     // (E,)
    const int*   mat_row    = (const int*)d_in[4];     // (NI,)
    const int*   mat_col    = (const int*)d_in[5];     // (NI,)
    // d_in[6] = mat_val: unused by the reference
    const float* weight     = (const float*)d_in[7];   // (32, 64)
    const float* gate1_w    = (const float*)d_in[8];   // (64, 64)
    const float* gate2_w    = (const float*)d_in[9];   // (64, 64)

    float* out = (float*)d_out;
    // output layout: entity_agg_out (100000*64) | user_agg (50000*64)
    float* out_fusion = out;                                // rows [0, 50000)
    float* out_entity = out;                                // rows [50000,100000) at row*64
    float* out_user   = out + (size_t)N_ENT * DD;           // 3.2M floats

    // workspace layout (floats)
    float* ent_acc = (float*)d_ws;                          // 6,400,000
    float* iu_acc  = ent_acc + (size_t)N_ENT * DD;          // 3,200,000
    float* cnt_e   = iu_acc + (size_t)N_ITEMS * DD;         // 100,000
    float* cnt_i   = cnt_e + N_ENT;                         // 50,000
    const size_t ws_floats = (size_t)N_ENT * DD + (size_t)N_ITEMS * DD + N_ENT + N_ITEMS;

    // Stage 1: zero accumulators + user_agg output region (every call).
    hipMemsetAsync(d_ws, 0, ws_floats * sizeof(float), stream);
    hipMemsetAsync(out_user, 0, (size_t)N_USERS * DD * sizeof(float), stream);

    const int*   head = edge_index;
    const int*   tail = edge_index + NE;

    // Stage 2: entity graph aggregation
    edge_agg_kernel<<<8192, 256, 0, stream>>>(entity_emb, head, tail, edge_type,
                                              weight, ent_acc, cnt_e);
    // Stage 3: user->item aggregation
    user_item_kernel<<<4096, 256, 0, stream>>>(user_emb, mat_row, mat_col,
                                               weight, iu_acc, cnt_i);
    // Stage 4: finalize means
    finalize_entity_kernel<<<(N_ENT * DD) / 256, 256, 0, stream>>>(ent_acc, cnt_e, out_entity);
    finalize_iu_kernel<<<(N_ITEMS * DD) / 256, 256, 0, stream>>>(iu_acc, cnt_i);
    // Stage 5: gate + fusion -> d_out rows [0, 50000)
    gate_fusion_kernel<<<N_ITEMS / 4, 256, 0, stream>>>(ent_acc, iu_acc,
                                                        gate1_w, gate2_w, out_fusion);
    // Stage 6: user_agg scatter-sum
    user_scatter_kernel<<<4096, 256, 0, stream>>>(out_fusion, mat_row, mat_col, out_user);
}

// Round 2
// 795.855 us; speedup vs baseline: 1.3483x; 1.3483x over previous
//
#include <hip/hip_runtime.h>
#include <hip/hip_bf16.h>

#define N_USERS   50000
#define N_ITEMS   50000
#define N_ENT     100000
#define NE        2000000
#define NNI       1000000
#define DD        64

// ---------------------------------------------------------------------------
// CSR build: histogram -> exclusive scan (3-stage) -> fill
// ---------------------------------------------------------------------------
__global__ void hist_kernel(const int* __restrict__ key, int n, int* __restrict__ cnt) {
    int i = blockIdx.x * blockDim.x + threadIdx.x;
    const int st = gridDim.x * blockDim.x;
    for (; i < n; i += st) atomicAdd(&cnt[key[i]], 1);
}

// stage 1: per-block (256 elems) exclusive scan; write block totals
__global__ void scan1_kernel(const int* __restrict__ cnt, int n,
                             int* __restrict__ off, int* __restrict__ bsums) {
    __shared__ int s[256];
    const int tid = threadIdx.x;
    const int gi = blockIdx.x * 256 + tid;
    const int x = (gi < n) ? cnt[gi] : 0;
    s[tid] = x; __syncthreads();
    for (int d = 1; d < 256; d <<= 1) {
        const int v = (tid >= d) ? s[tid - d] : 0;
        __syncthreads();
        s[tid] += v;
        __syncthreads();
    }
    if (gi < n) off[gi] = s[tid] - x;             // exclusive within block
    if (tid == 255) bsums[blockIdx.x] = s[255];   // block total
}

// stage 2: single-block exclusive scan of block totals (nb <= 512)
__global__ void scan2_kernel(int* __restrict__ bsums, int nb) {
    __shared__ int s[512];
    const int tid = threadIdx.x;
    const int x = (tid < nb) ? bsums[tid] : 0;
    s[tid] = x; __syncthreads();
    for (int d = 1; d < 512; d <<= 1) {
        const int v = (tid >= d) ? s[tid - d] : 0;
        __syncthreads();
        s[tid] += v;
        __syncthreads();
    }
    if (tid < nb) bsums[tid] = s[tid] - x;
}

// stage 3: add block offsets; init next[] = off[]; write off[n] = total
__global__ void scan3_kernel(int* __restrict__ off, int n,
                             const int* __restrict__ bsums,
                             int* __restrict__ nxt, int total) {
    const int gi = blockIdx.x * 256 + threadIdx.x;
    if (gi < n) {
        const int v = off[gi] + bsums[blockIdx.x];
        off[gi] = v;
        nxt[gi] = v;
    }
    if (gi == 0) off[n] = total;
}

__global__ void fill_kernel(const int* __restrict__ key, int n,
                            int* __restrict__ nxt, int* __restrict__ ids) {
    int i = blockIdx.x * blockDim.x + threadIdx.x;
    const int st = gridDim.x * blockDim.x;
    for (; i < n; i += st) {
        const int p = atomicAdd(&nxt[key[i]], 1);
        ids[p] = i;
    }
}

// ---------------------------------------------------------------------------
// Pull aggregations: one 64-lane wave per destination row; lane = feature dim.
// ---------------------------------------------------------------------------
__global__ void pull_entity_kernel(const float* __restrict__ ent,
                                   const int* __restrict__ tail,
                                   const int* __restrict__ etype,
                                   const float* __restrict__ wgt,
                                   const int* __restrict__ off,
                                   const int* __restrict__ ids,
                                   float* __restrict__ out) {
    const int lane = threadIdx.x & 63;
    const int wid = (blockIdx.x * blockDim.x + threadIdx.x) >> 6;
    if (wid >= N_ENT) return;
    const int beg = off[wid], end = off[wid + 1];
    float acc = 0.f;
    for (int base = beg; base < end; base += 64) {
        const int k = base + lane;
        int t = 0, r = 0;
        if (k < end) { const int e = ids[k]; t = tail[e]; r = etype[e]; }
        const int n = min(64, end - base);
        int kk = 0;
        for (; kk + 4 <= n; kk += 4) {
            const int t0 = __shfl(t, kk),     r0 = __shfl(r, kk);
            const int t1 = __shfl(t, kk + 1), r1 = __shfl(r, kk + 1);
            const int t2 = __shfl(t, kk + 2), r2 = __shfl(r, kk + 2);
            const int t3 = __shfl(t, kk + 3), r3 = __shfl(r, kk + 3);
            const float a0 = ent[(size_t)t0 * DD + lane] * wgt[r0 * DD + lane];
            const float a1 = ent[(size_t)t1 * DD + lane] * wgt[r1 * DD + lane];
            const float a2 = ent[(size_t)t2 * DD + lane] * wgt[r2 * DD + lane];
            const float a3 = ent[(size_t)t3 * DD + lane] * wgt[r3 * DD + lane];
            acc += a0 + a1 + a2 + a3;
        }
        for (; kk < n; ++kk) {
            const int tt = __shfl(t, kk), rr = __shfl(r, kk);
            acc += ent[(size_t)tt * DD + lane] * wgt[rr * DD + lane];
        }
    }
    const float d = (float)(end - beg);
    out[(size_t)wid * DD + lane] = acc / fmaxf(d, 1.0f);
}

__global__ void pull_iu_kernel(const float* __restrict__ uemb,
                               const int* __restrict__ mrow,
                               const float* __restrict__ wgt,
                               const int* __restrict__ off,
                               const int* __restrict__ ids,
                               float* __restrict__ iu_out) {
    const int lane = threadIdx.x & 63;
    const int wid = (blockIdx.x * blockDim.x + threadIdx.x) >> 6;
    if (wid >= N_ITEMS) return;
    const float w0 = wgt[lane];   // weight[0][lane], constant over the sum
    const int beg = off[wid], end = off[wid + 1];
    float acc = 0.f;
    for (int base = beg; base < end; base += 64) {
        const int k = base + lane;
        int t = 0;
        if (k < end) t = mrow[ids[k]];
        const int n = min(64, end - base);
        int kk = 0;
        for (; kk + 4 <= n; kk += 4) {
            const int t0 = __shfl(t, kk),     t1 = __shfl(t, kk + 1);
            const int t2 = __shfl(t, kk + 2), t3 = __shfl(t, kk + 3);
            acc += uemb[(size_t)t0 * DD + lane] + uemb[(size_t)t1 * DD + lane]
                 + uemb[(size_t)t2 * DD + lane] + uemb[(size_t)t3 * DD + lane];
        }
        for (; kk < n; ++kk) {
            const int tt = __shfl(t, kk);
            acc += uemb[(size_t)tt * DD + lane];
        }
    }
    const float d = (float)(end - beg);
    iu_out[(size_t)wid * DD + lane] = acc * w0 / fmaxf(d, 1.0f);
}

__global__ void pull_user_kernel(const float* __restrict__ fus,
                                 const int* __restrict__ mcol,
                                 const int* __restrict__ off,
                                 const int* __restrict__ ids,
                                 float* __restrict__ uout) {
    const int lane = threadIdx.x & 63;
    const int wid = (blockIdx.x * blockDim.x + threadIdx.x) >> 6;
    if (wid >= N_USERS) return;
    const int beg = off[wid], end = off[wid + 1];
    float acc = 0.f;
    for (int base = beg; base < end; base += 64) {
        const int k = base + lane;
        int t = 0;
        if (k < end) t = mcol[ids[k]];
        const int n = min(64, end - base);
        int kk = 0;
        for (; kk + 4 <= n; kk += 4) {
            const int t0 = __shfl(t, kk),     t1 = __shfl(t, kk + 1);
            const int t2 = __shfl(t, kk + 2), t3 = __shfl(t, kk + 3);
            acc += fus[(size_t)t0 * DD + lane] + fus[(size_t)t1 * DD + lane]
                 + fus[(size_t)t2 * DD + lane] + fus[(size_t)t3 * DD + lane];
        }
        for (; kk < n; ++kk) {
            const int tt = __shfl(t, kk);
            acc += fus[(size_t)tt * DD + lane];
        }
    }
    uout[(size_t)wid * DD + lane] = acc;   // segment_sum: no divide
}

// ---------------------------------------------------------------------------
// Gate + fusion, in place on d_out. 4 items / 256-thread block.
// ---------------------------------------------------------------------------
__global__ void gate_fusion_kernel(float* __restrict__ kg_fus,   // d_out rows [0,50000)
                                   const float* __restrict__ iu, // d_out user region (temp)
                                   const float* __restrict__ g1,
                                   const float* __restrict__ g2) {
    __shared__ float G1[64 * 65];
    __shared__ float G2[64 * 65];
    __shared__ float xs1[4][64];
    __shared__ float xs2[4][64];

    const int tid = threadIdx.x;
    for (int i = tid; i < 64 * 64; i += 256) {
        const int r = i >> 6, c = i & 63;
        G1[r * 65 + c] = g1[i];
        G2[r * 65 + c] = g2[i];
    }

    const int il = tid >> 6;
    const int j = tid & 63;
    const int item = blockIdx.x * 4 + il;

    const float x1 = kg_fus[(size_t)item * DD + j];
    const float x2 = iu[(size_t)item * DD + j];
    xs1[il][j] = x1;
    xs2[il][j] = x2;
    __syncthreads();

    float s = 0.0f;
    #pragma unroll
    for (int k = 0; k < 64; ++k) {
        s += xs1[il][k] * G1[j * 65 + k];
        s += xs2[il][k] * G2[j * 65 + k];
    }
    const float gi = 1.0f / (1.0f + __expf(-s));
    kg_fus[(size_t)item * DD + j] = gi * x1 + (1.0f - gi) * x2;
}

extern "C" void kernel_launch(void* const* d_in, const int* in_sizes, int n_in,
                              void* d_out, int out_size, void* d_ws, size_t ws_size,
                              hipStream_t stream) {
    const float* entity_emb = (const float*)d_in[0];
    const float* user_emb   = (const float*)d_in[1];
    const int*   edge_index = (const int*)d_in[2];
    const int*   edge_type  = (const int*)d_in[3];
    const int*   mat_row    = (const int*)d_in[4];
    const int*   mat_col    = (const int*)d_in[5];
    const float* weight     = (const float*)d_in[7];
    const float* gate1_w    = (const float*)d_in[8];
    const float* gate2_w    = (const float*)d_in[9];

    float* out = (float*)d_out;
    float* out_fusion = out;                       // rows [0, 50000): kg then fusion
    float* out_entity = out;                       // rows [0, 100000)
    float* out_user   = out + (size_t)N_ENT * DD;  // users; temporarily holds i_u_agg

    // workspace: all int32 CSR structures (~18.5 MB)
    int* cnt_e = (int*)d_ws;               // 100000
    int* cnt_c = cnt_e + N_ENT;            // 50000
    int* cnt_r = cnt_c + N_ITEMS;          // 50000
    int* off_e = cnt_r + N_USERS;          // 100001
    int* off_c = off_e + (N_ENT + 1);      // 50001
    int* off_r = off_c + (N_ITEMS + 1);    // 50001
    int* nxt_e = off_r + (N_USERS + 1);    // 100000
    int* nxt_c = nxt_e + N_ENT;            // 50000
    int* nxt_r = nxt_c + N_ITEMS;          // 50000
    int* ids_e = nxt_r + N_USERS;          // 2000000
    int* ids_c = ids_e + NE;               // 1000000
    int* ids_r = ids_c + NNI;              // 1000000
    int* bsums = ids_r + NNI;              // 512 scratch

    const int* head = edge_index;
    const int* tail = edge_index + NE;

    const int NB_E = (N_ENT + 255) / 256;     // 391
    const int NB_I = (N_ITEMS + 255) / 256;   // 196 (== users)

    // zero histogram counters (800 KB)
    hipMemsetAsync(cnt_e, 0, (size_t)(N_ENT + N_ITEMS + N_USERS) * sizeof(int), stream);

    // histograms
    hist_kernel<<<2048, 256, 0, stream>>>(head, NE, cnt_e);
    hist_kernel<<<2048, 256, 0, stream>>>(mat_col, NNI, cnt_c);
    hist_kernel<<<2048, 256, 0, stream>>>(mat_row, NNI, cnt_r);

    // scans (entity / col / row)
    scan1_kernel<<<NB_E, 256, 0, stream>>>(cnt_e, N_ENT, off_e, bsums);
    scan2_kernel<<<1, 512, 0, stream>>>(bsums, NB_E);
    scan3_kernel<<<NB_E, 256, 0, stream>>>(off_e, N_ENT, bsums, nxt_e, NE);

    scan1_kernel<<<NB_I, 256, 0, stream>>>(cnt_c, N_ITEMS, off_c, bsums);
    scan2_kernel<<<1, 512, 0, stream>>>(bsums, NB_I);
    scan3_kernel<<<NB_I, 256, 0, stream>>>(off_c, N_ITEMS, bsums, nxt_c, NNI);

    scan1_kernel<<<NB_I, 256, 0, stream>>>(cnt_r, N_USERS, off_r, bsums);
    scan2_kernel<<<1, 512, 0, stream>>>(bsums, NB_I);
    scan3_kernel<<<NB_I, 256, 0, stream>>>(off_r, N_USERS, bsums, nxt_r, NNI);

    // fills
    fill_kernel<<<2048, 256, 0, stream>>>(head, NE, nxt_e, ids_e);
    fill_kernel<<<2048, 256, 0, stream>>>(mat_col, NNI, nxt_c, ids_c);
    fill_kernel<<<2048, 256, 0, stream>>>(mat_row, NNI, nxt_r, ids_r);

    // pull aggregations
    pull_entity_kernel<<<N_ENT / 4, 256, 0, stream>>>(entity_emb, tail, edge_type,
                                                      weight, off_e, ids_e, out_entity);
    pull_iu_kernel<<<N_ITEMS / 4, 256, 0, stream>>>(user_emb, mat_row, weight,
                                                    off_c, ids_c, out_user);
    // gate + fusion (in place: kg -> fusion in d_out rows [0,50000))
    gate_fusion_kernel<<<N_ITEMS / 4, 256, 0, stream>>>(out_fusion, out_user,
                                                        gate1_w, gate2_w);
    // user_agg overwrites the temp i_u_agg region
    pull_user_kernel<<<N_USERS / 4, 256, 0, stream>>>(out_fusion, mat_col,
                                                      off_r, ids_r, out_user);
}

// Round 4
// 543.237 us; speedup vs baseline: 1.9753x; 1.4650x over previous
//
#include <hip/hip_runtime.h>
#include <hip/hip_bf16.h>

#define N_USERS   50000
#define N_ITEMS   50000
#define N_ENT     100000
#define NE        2000000
#define NNI       1000000
#define DD        64

#define PART_E    (N_ENT / 8)    // 12500 entity rows per XCD partition
#define PART_I    (N_ITEMS / 8)  // 6250  (items == users per-partition size)

#define NB_E      ((N_ENT  + 255) / 256)   // 391
#define NB_C      ((N_ITEMS + 255) / 256)  // 196
#define NB_R      ((N_USERS + 255) / 256)  // 196

// ---------------------------------------------------------------------------
// XCD-local histograms. blockIdx&7 ~ XCD (round-robin dispatch); each
// partition scans all keys but only touches counters in its own 1/8 range,
// so atomic lines stay resident in one L2.
// ---------------------------------------------------------------------------
__global__ void hist_edge_kernel(const int* __restrict__ head,
                                 int* __restrict__ cnt) {
    const int part = blockIdx.x & 7;
    const int lo = part * PART_E, hi = lo + PART_E;
    int i = (blockIdx.x >> 3) * blockDim.x + threadIdx.x;
    const int st = (gridDim.x >> 3) * blockDim.x;
    for (; i < NE; i += st) {
        const int h = head[i];
        if (h >= lo && h < hi) atomicAdd(&cnt[h], 1);
    }
}

__global__ void hist_mat_kernel(const int* __restrict__ mrow,
                                const int* __restrict__ mcol,
                                int* __restrict__ cnt_c,
                                int* __restrict__ cnt_r) {
    const int part = blockIdx.x & 7;
    const int lo = part * PART_I, hi = lo + PART_I;
    int i = (blockIdx.x >> 3) * blockDim.x + threadIdx.x;
    const int st = (gridDim.x >> 3) * blockDim.x;
    for (; i < NNI; i += st) {
        const int c = mcol[i];
        if (c >= lo && c < hi) atomicAdd(&cnt_c[c], 1);
        const int r = mrow[i];
        if (r >= lo && r < hi) atomicAdd(&cnt_r[r], 1);
    }
}

// ---------------------------------------------------------------------------
// Fused 3-segment exclusive scan: entity / col / row chains in one launch.
// ---------------------------------------------------------------------------
__global__ void scan1_all_kernel(const int* __restrict__ cnt_e,
                                 const int* __restrict__ cnt_c,
                                 const int* __restrict__ cnt_r,
                                 int* __restrict__ off_e, int* __restrict__ off_c,
                                 int* __restrict__ off_r,
                                 int* __restrict__ bs_e, int* __restrict__ bs_c,
                                 int* __restrict__ bs_r) {
    __shared__ int s[256];
    const int b = blockIdx.x;
    const int* cnt; int* off; int* bs; int n; int blk;
    if (b < NB_E)            { cnt = cnt_e; off = off_e; bs = bs_e; n = N_ENT;   blk = b; }
    else if (b < NB_E + NB_C){ cnt = cnt_c; off = off_c; bs = bs_c; n = N_ITEMS; blk = b - NB_E; }
    else                     { cnt = cnt_r; off = off_r; bs = bs_r; n = N_USERS; blk = b - NB_E - NB_C; }

    const int tid = threadIdx.x;
    const int gi = blk * 256 + tid;
    const int x = (gi < n) ? cnt[gi] : 0;
    s[tid] = x; __syncthreads();
    for (int d = 1; d < 256; d <<= 1) {
        const int v = (tid >= d) ? s[tid - d] : 0;
        __syncthreads();
        s[tid] += v;
        __syncthreads();
    }
    if (gi < n) off[gi] = s[tid] - x;
    if (tid == 255) bs[blk] = s[255];
}

__global__ void scan2_all_kernel(int* __restrict__ bs_e, int* __restrict__ bs_c,
                                 int* __restrict__ bs_r) {
    __shared__ int s[512];
    int* bs; int nb;
    if (blockIdx.x == 0)      { bs = bs_e; nb = NB_E; }
    else if (blockIdx.x == 1) { bs = bs_c; nb = NB_C; }
    else                      { bs = bs_r; nb = NB_R; }
    const int tid = threadIdx.x;
    const int x = (tid < nb) ? bs[tid] : 0;
    s[tid] = x; __syncthreads();
    for (int d = 1; d < 512; d <<= 1) {
        const int v = (tid >= d) ? s[tid - d] : 0;
        __syncthreads();
        s[tid] += v;
        __syncthreads();
    }
    if (tid < nb) bs[tid] = s[tid] - x;
}

__global__ void scan3_all_kernel(int* __restrict__ off_e, int* __restrict__ off_c,
                                 int* __restrict__ off_r,
                                 const int* __restrict__ bs_e,
                                 const int* __restrict__ bs_c,
                                 const int* __restrict__ bs_r,
                                 int* __restrict__ nxt_e, int* __restrict__ nxt_c,
                                 int* __restrict__ nxt_r) {
    const int b = blockIdx.x;
    int* off; const int* bs; int* nxt; int n; int blk; int total;
    if (b < NB_E)            { off = off_e; bs = bs_e; nxt = nxt_e; n = N_ENT;   blk = b;               total = NE; }
    else if (b < NB_E + NB_C){ off = off_c; bs = bs_c; nxt = nxt_c; n = N_ITEMS; blk = b - NB_E;        total = NNI; }
    else                     { off = off_r; bs = bs_r; nxt = nxt_r; n = N_USERS; blk = b - NB_E - NB_C; total = NNI; }
    const int gi = blk * 256 + threadIdx.x;
    if (gi < n) {
        const int v = off[gi] + bs[blk];
        off[gi] = v;
        nxt[gi] = v;
    }
    if (blk == 0 && threadIdx.x == 0) off[n] = total;
}

// ---------------------------------------------------------------------------
// XCD-local fills with packed payloads.
// edge: payload = tail | (etype << 17)   (tail < 2^17, etype < 32)
// mat : ids_c payload = mat_row, ids_r payload = mat_col
// ---------------------------------------------------------------------------
__global__ void fill_edge_kernel(const int* __restrict__ head,
                                 const int* __restrict__ tail,
                                 const int* __restrict__ etype,
                                 int* __restrict__ nxt, int* __restrict__ ids) {
    const int part = blockIdx.x & 7;
    const int lo = part * PART_E, hi = lo + PART_E;
    int i = (blockIdx.x >> 3) * blockDim.x + threadIdx.x;
    const int st = (gridDim.x >> 3) * blockDim.x;
    for (; i < NE; i += st) {
        const int h = head[i];
        if (h >= lo && h < hi) {
            const int p = atomicAdd(&nxt[h], 1);
            ids[p] = tail[i] | (etype[i] << 17);
        }
    }
}

__global__ void fill_mat_kernel(const int* __restrict__ mrow,
                                const int* __restrict__ mcol,
                                int* __restrict__ nxt_c, int* __restrict__ ids_c,
                                int* __restrict__ nxt_r, int* __restrict__ ids_r) {
    const int part = blockIdx.x & 7;
    const int lo = part * PART_I, hi = lo + PART_I;
    int i = (blockIdx.x >> 3) * blockDim.x + threadIdx.x;
    const int st = (gridDim.x >> 3) * blockDim.x;
    for (; i < NNI; i += st) {
        const int c = mcol[i];
        const int r = mrow[i];
        if (c >= lo && c < hi) {
            const int p = atomicAdd(&nxt_c[c], 1);
            ids_c[p] = r;
        }
        if (r >= lo && r < hi) {
            const int p = atomicAdd(&nxt_r[r], 1);
            ids_r[p] = c;
        }
    }
}

// ---------------------------------------------------------------------------
// Pull aggregations: one 64-lane wave per destination row; lane = feature dim.
// ---------------------------------------------------------------------------
__global__ void pull_entity_kernel(const float* __restrict__ ent,
                                   const float* __restrict__ wgt,
                                   const int* __restrict__ off,
                                   const int* __restrict__ ids,
                                   float* __restrict__ out) {
    const int lane = threadIdx.x & 63;
    const int wid = (blockIdx.x * blockDim.x + threadIdx.x) >> 6;
    if (wid >= N_ENT) return;
    const int beg = off[wid], end = off[wid + 1];
    float acc = 0.f;
    for (int base = beg; base < end; base += 64) {
        const int k = base + lane;
        int v = 0;
        if (k < end) v = ids[k];
        const int n = min(64, end - base);
        int kk = 0;
        for (; kk + 4 <= n; kk += 4) {
            const int v0 = __shfl(v, kk),     v1 = __shfl(v, kk + 1);
            const int v2 = __shfl(v, kk + 2), v3 = __shfl(v, kk + 3);
            const float a0 = ent[(size_t)(v0 & 0x1FFFF) * DD + lane] * wgt[(v0 >> 17) * DD + lane];
            const float a1 = ent[(size_t)(v1 & 0x1FFFF) * DD + lane] * wgt[(v1 >> 17) * DD + lane];
            const float a2 = ent[(size_t)(v2 & 0x1FFFF) * DD + lane] * wgt[(v2 >> 17) * DD + lane];
            const float a3 = ent[(size_t)(v3 & 0x1FFFF) * DD + lane] * wgt[(v3 >> 17) * DD + lane];
            acc += a0 + a1 + a2 + a3;
        }
        for (; kk < n; ++kk) {
            const int vv = __shfl(v, kk);
            acc += ent[(size_t)(vv & 0x1FFFF) * DD + lane] * wgt[(vv >> 17) * DD + lane];
        }
    }
    const float d = (float)(end - beg);
    out[(size_t)wid * DD + lane] = acc / fmaxf(d, 1.0f);
}

__global__ void pull_iu_kernel(const float* __restrict__ uemb,
                               const float* __restrict__ wgt,
                               const int* __restrict__ off,
                               const int* __restrict__ ids,
                               float* __restrict__ iu_out) {
    const int lane = threadIdx.x & 63;
    const int wid = (blockIdx.x * blockDim.x + threadIdx.x) >> 6;
    if (wid >= N_ITEMS) return;
    const float w0 = wgt[lane];
    const int beg = off[wid], end = off[wid + 1];
    float acc = 0.f;
    for (int base = beg; base < end; base += 64) {
        const int k = base + lane;
        int v = 0;
        if (k < end) v = ids[k];
        const int n = min(64, end - base);
        int kk = 0;
        for (; kk + 4 <= n; kk += 4) {
            const int v0 = __shfl(v, kk),     v1 = __shfl(v, kk + 1);
            const int v2 = __shfl(v, kk + 2), v3 = __shfl(v, kk + 3);
            acc += uemb[(size_t)v0 * DD + lane] + uemb[(size_t)v1 * DD + lane]
                 + uemb[(size_t)v2 * DD + lane] + uemb[(size_t)v3 * DD + lane];
        }
        for (; kk < n; ++kk) {
            const int vv = __shfl(v, kk);
            acc += uemb[(size_t)vv * DD + lane];
        }
    }
    const float d = (float)(end - beg);
    iu_out[(size_t)wid * DD + lane] = acc * w0 / fmaxf(d, 1.0f);
}

__global__ void pull_user_kernel(const float* __restrict__ fus,
                                 const int* __restrict__ off,
                                 const int* __restrict__ ids,
                                 float* __restrict__ uout) {
    const int lane = threadIdx.x & 63;
    const int wid = (blockIdx.x * blockDim.x + threadIdx.x) >> 6;
    if (wid >= N_USERS) return;
    const int beg = off[wid], end = off[wid + 1];
    float acc = 0.f;
    for (int base = beg; base < end; base += 64) {
        const int k = base + lane;
        int v = 0;
        if (k < end) v = ids[k];
        const int n = min(64, end - base);
        int kk = 0;
        for (; kk + 4 <= n; kk += 4) {
            const int v0 = __shfl(v, kk),     v1 = __shfl(v, kk + 1);
            const int v2 = __shfl(v, kk + 2), v3 = __shfl(v, kk + 3);
            acc += fus[(size_t)v0 * DD + lane] + fus[(size_t)v1 * DD + lane]
                 + fus[(size_t)v2 * DD + lane] + fus[(size_t)v3 * DD + lane];
        }
        for (; kk < n; ++kk) {
            const int vv = __shfl(v, kk);
            acc += fus[(size_t)vv * DD + lane];
        }
    }
    uout[(size_t)wid * DD + lane] = acc;   // segment_sum: no divide
}

// ---------------------------------------------------------------------------
// Gate + fusion, in place on d_out. 4 items / 256-thread block.
// ---------------------------------------------------------------------------
__global__ void gate_fusion_kernel(float* __restrict__ kg_fus,
                                   const float* __restrict__ iu,
                                   const float* __restrict__ g1,
                                   const float* __restrict__ g2) {
    __shared__ float G1[64 * 65];
    __shared__ float G2[64 * 65];
    __shared__ float xs1[4][64];
    __shared__ float xs2[4][64];

    const int tid = threadIdx.x;
    for (int i = tid; i < 64 * 64; i += 256) {
        const int r = i >> 6, c = i & 63;
        G1[r * 65 + c] = g1[i];
        G2[r * 65 + c] = g2[i];
    }

    const int il = tid >> 6;
    const int j = tid & 63;
    const int item = blockIdx.x * 4 + il;

    const float x1 = kg_fus[(size_t)item * DD + j];
    const float x2 = iu[(size_t)item * DD + j];
    xs1[il][j] = x1;
    xs2[il][j] = x2;
    __syncthreads();

    float s = 0.0f;
    #pragma unroll
    for (int k = 0; k < 64; ++k) {
        s += xs1[il][k] * G1[j * 65 + k];
        s += xs2[il][k] * G2[j * 65 + k];
    }
    const float gi = 1.0f / (1.0f + __expf(-s));
    kg_fus[(size_t)item * DD + j] = gi * x1 + (1.0f - gi) * x2;
}

extern "C" void kernel_launch(void* const* d_in, const int* in_sizes, int n_in,
                              void* d_out, int out_size, void* d_ws, size_t ws_size,
                              hipStream_t stream) {
    const float* entity_emb = (const float*)d_in[0];
    const float* user_emb   = (const float*)d_in[1];
    const int*   edge_index = (const int*)d_in[2];
    const int*   edge_type  = (const int*)d_in[3];
    const int*   mat_row    = (const int*)d_in[4];
    const int*   mat_col    = (const int*)d_in[5];
    const float* weight     = (const float*)d_in[7];
    const float* gate1_w    = (const float*)d_in[8];
    const float* gate2_w    = (const float*)d_in[9];

    float* out = (float*)d_out;
    float* out_fusion = out;                       // rows [0, 50000)
    float* out_entity = out;                       // rows [0, 100000)
    float* out_user   = out + (size_t)N_ENT * DD;  // temp i_u_agg, then user_agg

    // workspace (ints), ~18.4 MB; cnt_e/cnt_c/cnt_r contiguous for one memset
    int* W     = (int*)d_ws;
    int* cnt_e = W;                        // 100000
    int* cnt_c = W + 100000;               // 50000
    int* cnt_r = W + 150000;               // 50000
    int* off_e = W + 200000;               // 100001
    int* off_c = W + 300001;               // 50001
    int* off_r = W + 350002;               // 50001
    int* nxt_e = W + 400003;               // 100000
    int* nxt_c = W + 500003;               // 50000
    int* nxt_r = W + 550003;               // 50000
    int* ids_e = W + 600003;               // 2000000
    int* ids_c = W + 2600003;              // 1000000
    int* ids_r = W + 3600003;              // 1000000
    int* bs_e  = W + 4600003;              // 512
    int* bs_c  = W + 4600515;              // 512
    int* bs_r  = W + 4601027;              // 512

    const int* head = edge_index;
    const int* tail = edge_index + NE;

    // zero histogram counters (800 KB)
    (void)hipMemsetAsync(cnt_e, 0, (size_t)(N_ENT + N_ITEMS + N_USERS) * sizeof(int), stream);

    // XCD-local histograms
    hist_edge_kernel<<<2048, 256, 0, stream>>>(head, cnt_e);
    hist_mat_kernel <<<2048, 256, 0, stream>>>(mat_row, mat_col, cnt_c, cnt_r);

    // fused scans
    scan1_all_kernel<<<NB_E + NB_C + NB_R, 256, 0, stream>>>(cnt_e, cnt_c, cnt_r,
                                                             off_e, off_c, off_r,
                                                             bs_e, bs_c, bs_r);
    scan2_all_kernel<<<3, 512, 0, stream>>>(bs_e, bs_c, bs_r);
    scan3_all_kernel<<<NB_E + NB_C + NB_R, 256, 0, stream>>>(off_e, off_c, off_r,
                                                             bs_e, bs_c, bs_r,
                                                             nxt_e, nxt_c, nxt_r);

    // XCD-local fills (packed payloads)
    fill_edge_kernel<<<2048, 256, 0, stream>>>(head, tail, edge_type, nxt_e, ids_e);
    fill_mat_kernel <<<2048, 256, 0, stream>>>(mat_row, mat_col,
                                               nxt_c, ids_c, nxt_r, ids_r);

    // pull aggregations
    pull_entity_kernel<<<N_ENT / 4, 256, 0, stream>>>(entity_emb, weight,
                                                      off_e, ids_e, out_entity);
    pull_iu_kernel<<<N_ITEMS / 4, 256, 0, stream>>>(user_emb, weight,
                                                    off_c, ids_c, out_user);
    gate_fusion_kernel<<<N_ITEMS / 4, 256, 0, stream>>>(out_fusion, out_user,
                                                        gate1_w, gate2_w);
    pull_user_kernel<<<N_USERS / 4, 256, 0, stream>>>(out_fusion,
                                                      off_r, ids_r, out_user);
}